// Round 1
// baseline (201.011 us; speedup 1.0000x reference)
//
#include <hip/hip_runtime.h>
#include <math.h>

#define EPSF    1e-8f
#define SLOPEF  0.2f
#define GS_EPSF 1e-6f

#define NB   4      // batch b
#define KZ   4      // noise replicates k
#define BKT  16     // NB*KZ
#define NPT  2048   // points
#define DIM  32
#define KNN  4

// ---------------------------------------------------------------------------
// Kernel 0: coords[bk][c][n] (c=0..5: features, c=6: sum of squares), stride 8 rows
// ---------------------------------------------------------------------------
__global__ __launch_bounds__(256) void prep_coords(
    const float* __restrict__ node, const float* __restrict__ z,
    float* __restrict__ coords) {
  int t = blockIdx.x * 256 + threadIdx.x;            // 32768 points total
  if (t >= BKT * NPT) return;
  int bk = t >> 11, n = t & (NPT - 1);
  int b = bk >> 2, kz = bk & 3;
  float xx = 0.f;
#pragma unroll
  for (int c = 0; c < 2; ++c)
#pragma unroll
    for (int j = 0; j < 3; ++j) {
      float v = node[((b * NPT + n) * 3 + j) * 2 + c]
              + z[(((b * KZ + kz) * NPT + n) * 3 + j) * 2 + c];
      coords[(bk * 8 + c * 3 + j) * NPT + n] = v;
      xx = fmaf(v, v, xx);
    }
  coords[(bk * 8 + 6) * NPT + n] = xx;
}

// ---------------------------------------------------------------------------
// Kernel 1: top-4 KNN per query (neg_dist = 2*inner - xx_i - xx_j, ties -> lower idx)
// ---------------------------------------------------------------------------
__device__ __forceinline__ void ce(float& vx, int& ix, float& vy, int& iy) {
  float av = vx, bv = vy; int ai = ix, bi = iy;
  bool sw = (bv > av) || (bv == av && bi < ai);
  vx = sw ? bv : av; vy = sw ? av : bv;
  ix = sw ? bi : ai; iy = sw ? ai : bi;
}

__global__ __launch_bounds__(256) void knn_kernel(
    const float* __restrict__ coords, int* __restrict__ knn) {
  __shared__ float sc[7][NPT];                       // 57344 B, SoA: conflict-free
  int bk = blockIdx.x >> 5;
  int qb = (blockIdx.x & 31) << 6;                   // 64 queries per block
  const float* cb = coords + bk * 8 * NPT;
  for (int i = threadIdx.x; i < NPT; i += 256) {
#pragma unroll
    for (int c = 0; c < 7; ++c) sc[c][i] = cb[c * NPT + i];
  }
  __syncthreads();
  int wave = threadIdx.x >> 6, lane = threadIdx.x & 63;
  for (int qt = 0; qt < 16; ++qt) {
    int q = qb + wave * 16 + qt;
    float c0 = sc[0][q], c1 = sc[1][q], c2 = sc[2][q];
    float c3 = sc[3][q], c4 = sc[4][q], c5 = sc[5][q];
    float xq = sc[6][q];
    float v0 = -INFINITY, v1 = -INFINITY, v2 = -INFINITY, v3 = -INFINITY;
    int   i0 = 0x7fffffff, i1 = 0x7fffffff, i2 = 0x7fffffff, i3 = 0x7fffffff;
    for (int t = 0; t < NPT / 64; ++t) {
      int j = t * 64 + lane;
      float in_ = c0 * sc[0][j];
      in_ = fmaf(c1, sc[1][j], in_);
      in_ = fmaf(c2, sc[2][j], in_);
      in_ = fmaf(c3, sc[3][j], in_);
      in_ = fmaf(c4, sc[4][j], in_);
      in_ = fmaf(c5, sc[5][j], in_);
      float nd = 2.f * in_ - xq - sc[6][j];
      // per-lane sorted insert; j ascending => strict '>' keeps lower-index-first
      if (nd > v3) {
        if (nd > v2) {
          v3 = v2; i3 = i2;
          if (nd > v1) {
            v2 = v1; i2 = i1;
            if (nd > v0) { v1 = v0; i1 = i0; v0 = nd; i0 = j; }
            else         { v1 = nd; i1 = j; }
          } else { v2 = nd; i2 = j; }
        } else { v3 = nd; i3 = j; }
      }
    }
    // butterfly merge of sorted-4 lists (bitonic top-4, 8 CEs per step)
#pragma unroll
    for (int off = 1; off < 64; off <<= 1) {
      float b0 = __shfl_xor(v0, off), b1 = __shfl_xor(v1, off);
      float b2 = __shfl_xor(v2, off), b3 = __shfl_xor(v3, off);
      int   j0 = __shfl_xor(i0, off), j1 = __shfl_xor(i1, off);
      int   j2 = __shfl_xor(i2, off), j3 = __shfl_xor(i3, off);
      float s4 = b3, s5 = b2, s6 = b1, s7 = b0;
      int   t4 = j3, t5 = j2, t6 = j1, t7 = j0;
      ce(v0, i0, s4, t4); ce(v1, i1, s5, t5);
      ce(v2, i2, s6, t6); ce(v3, i3, s7, t7);
      ce(v0, i0, v2, i2); ce(v1, i1, v3, i3);
      ce(v0, i0, v1, i1); ce(v2, i2, v3, i3);
    }
    if (lane == 0) {
      *reinterpret_cast<int4*>(knn + (bk * NPT + q) * 4) = make_int4(i0, i1, i2, i3);
    }
  }
}

// ---------------------------------------------------------------------------
// Kernel 2: per point: G -> p,d -> leaky -> h; pool over k -> x1; dot3 for pool-N
// thread = (p_local, o); 4 points per 128-thread block
// ---------------------------------------------------------------------------
__global__ __launch_bounds__(128) void feature_kernel(
    const float* __restrict__ coords, const int* __restrict__ knn,
    const float* __restrict__ W1f, const float* __restrict__ W1d,
    const float* __restrict__ Wp1, const float* __restrict__ Wp3,
    float4* __restrict__ x1d) {
  __shared__ float4 hlds[4][KNN][DIM];   // [p][kk][c]
  __shared__ float4 x1lds[4][DIM];       // [p][c]
  __shared__ float  wp1T[DIM * DIM], wp3T[DIM * DIM];   // transposed: [c][o]
  for (int i = threadIdx.x; i < DIM * DIM; i += 128) {
    int o = i & 31, c = i >> 5;
    wp1T[i] = Wp1[o * 32 + c];
    wp3T[i] = Wp3[o * 32 + c];
  }
  int p = threadIdx.x >> 5, o = threadIdx.x & 31;
  int pg = blockIdx.x * 4 + p;
  int bk = pg >> 11, n = pg & (NPT - 1);
  const float* cb = coords + bk * 8 * NPT;
  float ct[6];
#pragma unroll
  for (int c = 0; c < 6; ++c) ct[c] = cb[c * NPT + n];
  float4 wf = reinterpret_cast<const float4*>(W1f)[o];
  float4 wd = reinterpret_cast<const float4*>(W1d)[o];
  float w1f[4] = {wf.x, wf.y, wf.z, wf.w};
  float w1d[4] = {wd.x, wd.y, wd.z, wd.w};
  int4 nb = *reinterpret_cast<const int4*>(knn + (bk * NPT + n) * 4);
  int nbi[4] = {nb.x, nb.y, nb.z, nb.w};
  float h[4][3];
#pragma unroll
  for (int kk = 0; kk < 4; ++kk) {
    int m = nbi[kk];
    float G[4][3];
#pragma unroll
    for (int j = 0; j < 3; ++j) {
      float n0 = cb[(0 + j) * NPT + m], n1 = cb[(3 + j) * NPT + m];
      G[0][j] = n0 - ct[j];
      G[1][j] = n1 - ct[3 + j];
      G[2][j] = ct[j];
      G[3][j] = ct[3 + j];
    }
    float pv[3], dv[3];
#pragma unroll
    for (int j = 0; j < 3; ++j) {
      float a = 0.f, dd = 0.f;
#pragma unroll
      for (int c = 0; c < 4; ++c) { a = fmaf(w1f[c], G[c][j], a); dd = fmaf(w1d[c], G[c][j], dd); }
      pv[j] = a; dv[j] = dd;
    }
    float dot = pv[0] * dv[0] + pv[1] * dv[1] + pv[2] * dv[2];
    float d2  = dv[0] * dv[0] + dv[1] * dv[1] + dv[2] * dv[2];
    float fac = dot / (d2 + EPSF);
#pragma unroll
    for (int j = 0; j < 3; ++j) {
      float negj = pv[j] - fac * dv[j];
      float sel = (dot >= 0.f) ? pv[j] : negj;
      h[kk][j] = SLOPEF * pv[j] + (1.f - SLOPEF) * sel;
    }
    hlds[p][kk][o] = make_float4(h[kk][0], h[kk][1], h[kk][2], 0.f);
  }
  __syncthreads();
  // d1 = Wp1 @ h  (per kk, per j)
  float d1[4][3] = {};
  for (int c = 0; c < 32; ++c) {
    float wp = wp1T[c * 32 + o];
#pragma unroll
    for (int kk = 0; kk < 4; ++kk) {
      float4 hv = hlds[p][kk][c];
      d1[kk][0] = fmaf(wp, hv.x, d1[kk][0]);
      d1[kk][1] = fmaf(wp, hv.y, d1[kk][1]);
      d1[kk][2] = fmaf(wp, hv.z, d1[kk][2]);
    }
  }
  // argmax over k (first occurrence)
  float best = -INFINITY;
  float x1[3] = {0.f, 0.f, 0.f};
#pragma unroll
  for (int kk = 0; kk < 4; ++kk) {
    float dt = h[kk][0] * d1[kk][0] + h[kk][1] * d1[kk][1] + h[kk][2] * d1[kk][2];
    if (dt > best) { best = dt; x1[0] = h[kk][0]; x1[1] = h[kk][1]; x1[2] = h[kk][2]; }
  }
  x1lds[p][o] = make_float4(x1[0], x1[1], x1[2], 0.f);
  __syncthreads();
  // d3 = Wp3 @ x1 ; dot3 = x1 . d3
  float d3[3] = {0.f, 0.f, 0.f};
  for (int c = 0; c < 32; ++c) {
    float wp = wp3T[c * 32 + o];
    float4 xv = x1lds[p][c];
    d3[0] = fmaf(wp, xv.x, d3[0]);
    d3[1] = fmaf(wp, xv.y, d3[1]);
    d3[2] = fmaf(wp, xv.z, d3[2]);
  }
  float dot3 = x1[0] * d3[0] + x1[1] * d3[1] + x1[2] * d3[2];
  x1d[(bk * NPT + n) * 32 + o] = make_float4(x1[0], x1[1], x1[2], dot3);
}

// ---------------------------------------------------------------------------
// Kernel 3: argmax over n per (bk,o), first-index tie-break; gather winner x1
// ---------------------------------------------------------------------------
__global__ __launch_bounds__(256) void pool_kernel(
    const float4* __restrict__ x1d, float* __restrict__ pooled) {
  int pair = blockIdx.x * 4 + (threadIdx.x >> 6);    // 512 (bk,o) pairs
  int lane = threadIdx.x & 63;
  int bk = pair >> 5, o = pair & 31;
  const float* x1f = reinterpret_cast<const float*>(x1d);
  float best = -INFINITY; int bestn = 0x7fffffff;
  for (int t = 0; t < NPT / 64; ++t) {
    int n = t * 64 + lane;
    float v = x1f[((bk * NPT + n) * 32 + o) * 4 + 3];
    if (v > best) { best = v; bestn = n; }
  }
#pragma unroll
  for (int off = 1; off < 64; off <<= 1) {
    float ov = __shfl_xor(best, off);
    int   on = __shfl_xor(bestn, off);
    if (ov > best || (ov == best && on < bestn)) { best = ov; bestn = on; }
  }
  if (lane == 0) {
    float4 xv = x1d[(bk * NPT + bestn) * 32 + o];
    pooled[(bk * 32 + o) * 3 + 0] = xv.x;
    pooled[(bk * 32 + o) * 3 + 1] = xv.y;
    pooled[(bk * 32 + o) * 3 + 2] = xv.z;
  }
}

// ---------------------------------------------------------------------------
// Kernel 4: pk = Wh2 @ pooled ; +GS_EPS*noise ; Gram-Schmidt ; det flip
// ---------------------------------------------------------------------------
__global__ __launch_bounds__(64) void head_kernel(
    const float* __restrict__ pooled, const float* __restrict__ Wh2,
    const float* __restrict__ gs, float* __restrict__ out) {
  int bk = threadIdx.x;
  if (bk >= BKT) return;
  float M[3][3];                                     // M[r=j][c=o]
#pragma unroll
  for (int oo = 0; oo < 3; ++oo) {
    float a0 = 0.f, a1 = 0.f, a2 = 0.f;
    for (int c = 0; c < 32; ++c) {
      float w = Wh2[oo * 32 + c];
      a0 = fmaf(w, pooled[(bk * 32 + c) * 3 + 0], a0);
      a1 = fmaf(w, pooled[(bk * 32 + c) * 3 + 1], a1);
      a2 = fmaf(w, pooled[(bk * 32 + c) * 3 + 2], a2);
    }
    M[0][oo] = a0 + GS_EPSF * gs[bk * 9 + 0 * 3 + oo];
    M[1][oo] = a1 + GS_EPSF * gs[bk * 9 + 1 * 3 + oo];
    M[2][oo] = a2 + GS_EPSF * gs[bk * 9 + 2 * 3 + oo];
  }
  float e1[3], e2[3], e3[3], u[3];
  float nn = sqrtf(M[0][0] * M[0][0] + M[1][0] * M[1][0] + M[2][0] * M[2][0]) + EPSF;
#pragma unroll
  for (int r = 0; r < 3; ++r) e1[r] = M[r][0] / nn;
  float d12 = e1[0] * M[0][1] + e1[1] * M[1][1] + e1[2] * M[2][1];
#pragma unroll
  for (int r = 0; r < 3; ++r) u[r] = M[r][1] - d12 * e1[r];
  nn = sqrtf(u[0] * u[0] + u[1] * u[1] + u[2] * u[2]) + EPSF;
#pragma unroll
  for (int r = 0; r < 3; ++r) e2[r] = u[r] / nn;
  float d13 = e1[0] * M[0][2] + e1[1] * M[1][2] + e1[2] * M[2][2];
  float d23 = e2[0] * M[0][2] + e2[1] * M[1][2] + e2[2] * M[2][2];
#pragma unroll
  for (int r = 0; r < 3; ++r) u[r] = M[r][2] - d13 * e1[r] - d23 * e2[r];
  nn = sqrtf(u[0] * u[0] + u[1] * u[1] + u[2] * u[2]) + EPSF;
#pragma unroll
  for (int r = 0; r < 3; ++r) e3[r] = u[r] / nn;
  float det = e1[0] * (e2[1] * e3[2] - e2[2] * e3[1])
            - e1[1] * (e2[0] * e3[2] - e2[2] * e3[0])
            + e1[2] * (e2[0] * e3[1] - e2[1] * e3[0]);
#pragma unroll
  for (int r = 0; r < 3; ++r) {
    out[bk * 9 + r * 3 + 0] = e1[r] * det;
    out[bk * 9 + r * 3 + 1] = e2[r];
    out[bk * 9 + r * 3 + 2] = e3[r];
  }
}

// ---------------------------------------------------------------------------
extern "C" void kernel_launch(void* const* d_in, const int* in_sizes, int n_in,
                              void* d_out, int out_size, void* d_ws, size_t ws_size,
                              hipStream_t stream) {
  (void)in_sizes; (void)n_in; (void)out_size; (void)ws_size;
  const float* node = (const float*)d_in[0];
  // d_in[1] = edge_features (unused by reference), d_in[2] = idx, d_in[3] = k (unused)
  const float* W1f = (const float*)d_in[4];
  const float* W1d = (const float*)d_in[5];
  const float* Wp1 = (const float*)d_in[6];
  const float* Wp3 = (const float*)d_in[7];
  const float* Wh2 = (const float*)d_in[8];
  const float* z   = (const float*)d_in[9];
  const float* gs  = (const float*)d_in[10];

  float* ws = (float*)d_ws;
  float*  coords = ws;                                   // 16*8*2048      = 262144 f
  int*    knn    = (int*)(ws + BKT * 8 * NPT);           // 16*2048*4      = 131072 i
  float4* x1d    = (float4*)(ws + BKT * 8 * NPT + BKT * NPT * 4);  // 16*2048*32 f4
  float*  pooled = ws + BKT * 8 * NPT + BKT * NPT * 4 + BKT * NPT * 32 * 4; // 1536 f
  float*  out    = (float*)d_out;

  prep_coords   <<<BKT * NPT / 256, 256, 0, stream>>>(node, z, coords);
  knn_kernel    <<<BKT * (NPT / 64), 256, 0, stream>>>(coords, knn);
  feature_kernel<<<BKT * NPT / 4, 128, 0, stream>>>(coords, knn, W1f, W1d, Wp1, Wp3, x1d);
  pool_kernel   <<<512 / 4, 256, 0, stream>>>(x1d, pooled);
  head_kernel   <<<1, 64, 0, stream>>>(pooled, Wh2, gs, out);
}